// Round 2
// baseline (694.116 us; speedup 1.0000x reference)
//
#include <hip/hip_runtime.h>

// x: (8,32,512,512) f32; A: 8x8 DCT; mask: 8x8 (low0 -> single nonzero).
// Per 8x8 tile X: L = A^T * (mask o (A * X * A^T)) * A ; out = (L, X - L).
// One thread per tile. Mask-sparse accumulation: for each nonzero mask[i][k]
// (wave-uniform branch), c = A[i,:] . X . A[k,:]^T ; L += c * outer(A[i,:],A[k,:]).
// Memory-bound: 768 MB total traffic -> ~122 us floor at 6.3 TB/s.

#define IMG_W 512u
#define HALF_ELEMS 67108864u     // 8*32*512*512

__global__ __launch_bounds__(256) void dct_lowpass_kernel(
    const float* __restrict__ x,
    const float* __restrict__ A,
    const float* __restrict__ mask,
    float* __restrict__ xlow,
    float* __restrict__ xhigh)
{
    const unsigned gid = blockIdx.x * 256u + threadIdx.x;  // tile id
    const unsigned nc  = gid >> 12;          // image (n*c) index
    const unsigned rem = gid & 4095u;
    const unsigned bh  = rem >> 6;           // block row
    const unsigned bw  = rem & 63u;          // block col
    const size_t base = ((size_t)nc * 512u + bh * 8u) * 512u + bw * 8u;

    // Load tile X (8 rows x 8 floats; per row 2x float4, 32B-aligned).
    float X[8][8];
#pragma unroll
    for (int r = 0; r < 8; ++r) {
        const float4* p = reinterpret_cast<const float4*>(x + base + (size_t)r * IMG_W);
        float4 a = p[0];
        float4 b = p[1];
        X[r][0] = a.x; X[r][1] = a.y; X[r][2] = a.z; X[r][3] = a.w;
        X[r][4] = b.x; X[r][5] = b.y; X[r][6] = b.z; X[r][7] = b.w;
    }

    float L[8][8];
#pragma unroll
    for (int j = 0; j < 8; ++j)
#pragma unroll
        for (int l = 0; l < 8; ++l) L[j][l] = 0.f;

    // Sparse-mask accumulation. mask/A accesses are wave-uniform with
    // compile-time offsets -> scalar loads (SGPRs), no VGPR cost.
#pragma unroll
    for (int i = 0; i < 8; ++i) {
#pragma unroll
        for (int k = 0; k < 8; ++k) {
            const float m = mask[i * 8 + k];
            if (m != 0.0f) {  // wave-uniform branch: all lanes agree
                // c = sum_j A[i,j] * (sum_l X[j,l] * A[k,l])
                float c = 0.f;
#pragma unroll
                for (int j = 0; j < 8; ++j) {
                    float r = 0.f;
#pragma unroll
                    for (int l = 0; l < 8; ++l) r = fmaf(X[j][l], A[k * 8 + l], r);
                    c = fmaf(A[i * 8 + j], r, c);
                }
                c *= m;
                // L[j][l] += c * A[i,j] * A[k,l]
#pragma unroll
                for (int j = 0; j < 8; ++j) {
                    const float cj = c * A[i * 8 + j];
#pragma unroll
                    for (int l = 0; l < 8; ++l)
                        L[j][l] = fmaf(cj, A[k * 8 + l], L[j][l]);
                }
            }
        }
    }

    // Write xlow = L, xhigh = X - L (row = 2x float4 each).
#pragma unroll
    for (int r = 0; r < 8; ++r) {
        float4 lo0 = make_float4(L[r][0], L[r][1], L[r][2], L[r][3]);
        float4 lo1 = make_float4(L[r][4], L[r][5], L[r][6], L[r][7]);
        float4 hi0 = make_float4(X[r][0] - L[r][0], X[r][1] - L[r][1],
                                 X[r][2] - L[r][2], X[r][3] - L[r][3]);
        float4 hi1 = make_float4(X[r][4] - L[r][4], X[r][5] - L[r][5],
                                 X[r][6] - L[r][6], X[r][7] - L[r][7]);
        float4* pl = reinterpret_cast<float4*>(xlow + base + (size_t)r * IMG_W);
        float4* ph = reinterpret_cast<float4*>(xhigh + base + (size_t)r * IMG_W);
        pl[0] = lo0; pl[1] = lo1;
        ph[0] = hi0; ph[1] = hi1;
    }
}

extern "C" void kernel_launch(void* const* d_in, const int* in_sizes, int n_in,
                              void* d_out, int out_size, void* d_ws, size_t ws_size,
                              hipStream_t stream) {
    const float* x    = (const float*)d_in[0];
    const float* A    = (const float*)d_in[1];
    const float* mask = (const float*)d_in[2];
    float* xlow  = (float*)d_out;
    float* xhigh = (float*)d_out + HALF_ELEMS;

    dim3 grid(4096);   // 1,048,576 tiles / 256 threads
    dim3 block(256);
    hipLaunchKernelGGL(dct_lowpass_kernel, grid, block, 0, stream,
                       x, A, mask, xlow, xhigh);
}